// Round 12
// baseline (265.603 us; speedup 1.0000x reference)
//
#include <hip/hip_runtime.h>
#include <cstdint>

#define N_TOT 1572864
#define KSEL 4096
#define CAP 8192
#define BINS 4096
#define SCORE_THR 0.5f
#define IOU_THR 0.1f
#define STAGE 512

__device__ inline uint64_t readlane64(uint64_t v, int lane) {
    uint32_t lo = (uint32_t)__builtin_amdgcn_readlane((int)(uint32_t)v, lane);
    uint32_t hi = (uint32_t)__builtin_amdgcn_readlane((int)(uint32_t)(v >> 32), lane);
    return ((uint64_t)hi << 32) | lo;
}

// ---------------- init: zero hist/counters/topScore ----------------
__global__ void k_init(uint32_t* hist, uint32_t* ctrs, float* topScore) {
    int i = blockIdx.x * blockDim.x + threadIdx.x;
    if (i < BINS) hist[i] = 0;
    if (i < 16) ctrs[i] = 0;
    if (i < KSEL) topScore[i] = 0.0f;
}

// ---------------- histogram over score bits (scores in (0.5,1)), float4 stream ----------------
__global__ void k_hist(const float4* __restrict__ cls4, uint32_t* __restrict__ hist) {
    int i = blockIdx.x * blockDim.x + threadIdx.x;
    int stride = gridDim.x * blockDim.x;
    for (; i < N_TOT / 2; i += stride) {
        float4 c = cls4[i];
        if (c.y > SCORE_THR) {
            uint32_t bin = (__float_as_uint(c.y) - 0x3F000000u) >> 11;
            if (bin >= BINS) bin = BINS - 1;
            atomicAdd(&hist[bin], 1u);
        }
        if (c.w > SCORE_THR) {
            uint32_t bin = (__float_as_uint(c.w) - 0x3F000000u) >> 11;
            if (bin >= BINS) bin = BINS - 1;
            atomicAdd(&hist[bin], 1u);
        }
    }
}

// ---------------- find cutoff bin T: largest b with suffix(b) >= K ----------------
__global__ __launch_bounds__(1024) void k_thresh(const uint32_t* __restrict__ hist,
                                                 uint32_t* __restrict__ ctrs) {
    __shared__ uint32_t s_suf[1024];
    int t = threadIdx.x;
    uint32_t l0 = hist[t*4+0], l1 = hist[t*4+1], l2 = hist[t*4+2], l3 = hist[t*4+3];
    s_suf[t] = l0 + l1 + l2 + l3;
    __syncthreads();
    for (int off = 1; off < 1024; off <<= 1) {
        uint32_t v = (t + off < 1024) ? s_suf[t + off] : 0u;
        __syncthreads();
        s_suf[t] += v;
        __syncthreads();
    }
    uint32_t snext = (t < 1023) ? s_suf[t + 1] : 0u;
    uint32_t suf3 = snext + l3;
    uint32_t suf2 = suf3 + l2;
    uint32_t suf1 = suf2 + l1;
    uint32_t suf0 = suf1 + l0;
    uint32_t sufs[5] = {suf0, suf1, suf2, suf3, snext};
    #pragma unroll
    for (int q = 0; q < 4; q++) {
        if (sufs[q] >= KSEL && sufs[q+1] < KSEL) ctrs[1] = (uint32_t)(t*4 + q);
    }
    if (t == 0 && s_suf[0] < KSEL) ctrs[1] = 0;  // fewer than K candidates
}

// ---------------- gather candidates (bin >= T) via LDS staging; 1 global atomic/block ----------------
__global__ void k_gather(const float4* __restrict__ cls4, uint32_t* __restrict__ ctrs,
                         uint64_t* __restrict__ keys) {
    __shared__ uint32_t s_cnt;
    __shared__ uint32_t s_base;
    __shared__ uint64_t s_stage[STAGE];
    if (threadIdx.x == 0) s_cnt = 0;
    __syncthreads();

    uint32_t T = ctrs[1];
    uint32_t basebits = 0x3F000000u + (T << 11);
    int i = blockIdx.x * blockDim.x + threadIdx.x;
    int stride = gridDim.x * blockDim.x;
    for (; i < N_TOT / 2; i += stride) {
        float4 c = cls4[i];
        #pragma unroll
        for (int h = 0; h < 2; h++) {
            float s = h ? c.w : c.y;
            uint32_t idx = 2u * (uint32_t)i + (uint32_t)h;
            if (s > SCORE_THR) {
                uint32_t b = __float_as_uint(s);
                if (b >= basebits) {
                    uint64_t key = ((uint64_t)b << 32) | (uint32_t)(~idx);
                    uint32_t p = atomicAdd(&s_cnt, 1u);
                    if (p < STAGE) s_stage[p] = key;
                    else {  // overflow: rare fallback, correctness-preserving
                        uint32_t g = atomicAdd(&ctrs[0], 1u);
                        if (g < CAP) keys[g] = key;
                    }
                }
            }
        }
    }
    __syncthreads();
    uint32_t n = s_cnt < STAGE ? s_cnt : STAGE;
    if (threadIdx.x == 0 && n > 0) s_base = atomicAdd(&ctrs[0], n);
    __syncthreads();
    for (uint32_t q = threadIdx.x; q < n; q += blockDim.x) {
        uint32_t g = s_base + q;
        if (g < CAP) keys[g] = s_stage[q];
    }
}

// ---------------- exact rank sort + fused decode (numpy f32 rounding, no FMA) ----------------
__global__ void k_rankdec(const uint64_t* __restrict__ keys, const uint32_t* __restrict__ ctrs,
                          const float* __restrict__ anchors, const float* __restrict__ reg,
                          float* __restrict__ topScore, float* __restrict__ boxes,
                          float* __restrict__ areas) {
    __shared__ uint64_t s_keys[256];
    uint32_t M = ctrs[0]; if (M > CAP) M = CAP;
    int j = blockIdx.x * blockDim.x + threadIdx.x;
    uint64_t myKey = (j < (int)M) ? keys[j] : 0ull;
    uint32_t rank = 0;
    for (uint32_t base = 0; base < M; base += 256) {
        uint32_t idx = base + threadIdx.x;
        s_keys[threadIdx.x] = (idx < M) ? keys[idx] : 0ull;
        __syncthreads();
        uint32_t lim = min(256u, M - base);
        for (uint32_t q = 0; q < lim; q++)
            rank += (s_keys[q] > myKey) ? 1u : 0u;
        __syncthreads();
    }
    if (j < (int)M && rank < KSEL) {
        uint32_t srcIdx = ~((uint32_t)(myKey & 0xFFFFFFFFull));
        topScore[rank] = __uint_as_float((uint32_t)(myKey >> 32));
        float4 a = *reinterpret_cast<const float4*>(&anchors[(size_t)srcIdx * 4]);
        float4 dd = *reinterpret_cast<const float4*>(&reg[(size_t)srcIdx * 4]);
        float d0 = __fmul_rn(dd.x, 0.1f);
        float d1 = __fmul_rn(dd.y, 0.1f);
        float d2 = __fmul_rn(dd.z, 0.2f);
        float d3 = __fmul_rn(dd.w, 0.2f);
        float w  = __fsub_rn(a.z, a.x);
        float h  = __fsub_rn(a.w, a.y);
        float cx = __fadd_rn(a.x, __fmul_rn(0.5f, w));
        float cy = __fadd_rn(a.y, __fmul_rn(0.5f, h));
        float pcx = __fadd_rn(cx, __fmul_rn(d0, w));
        float pcy = __fadd_rn(cy, __fmul_rn(d1, h));
        float pw = __fmul_rn((float)exp((double)d2), w);
        float ph = __fmul_rn((float)exp((double)d3), h);
        float x0 = __fsub_rn(pcx, __fmul_rn(0.5f, pw));
        float y0 = __fsub_rn(pcy, __fmul_rn(0.5f, ph));
        float x1 = __fadd_rn(pcx, __fmul_rn(0.5f, pw));
        float y1 = __fadd_rn(pcy, __fmul_rn(0.5f, ph));
        x0 = fminf(fmaxf(x0, 0.0f), 1024.0f);
        y0 = fminf(fmaxf(y0, 0.0f), 1024.0f);
        x1 = fminf(fmaxf(x1, 0.0f), 1024.0f);
        y1 = fminf(fmaxf(y1, 0.0f), 1024.0f);
        *reinterpret_cast<float4*>(&boxes[(size_t)rank * 4]) = make_float4(x0, y0, x1, y1);
        areas[rank] = __fmul_rn(__fsub_rn(x1, x0), __fsub_rn(y1, y0));
    }
}

// ---------------- pairwise suppression bitmask; lower-triangle blocks write 0 ----------------
__global__ void k_mask(const float* __restrict__ boxes, const float* __restrict__ areas,
                       unsigned long long* __restrict__ rowmask) {
    int bi = blockIdx.y, bj = blockIdx.x;
    int t = threadIdx.x;
    if (bj < bi) {  // zero-fill so reduce can AND rows unguarded
        rowmask[(size_t)(bi * 64 + t) * 64 + bj] = 0ull;
        return;
    }
    __shared__ float s_box[64][4];
    __shared__ float s_area[64];
    int r0 = bi * 64 + t;
    s_box[t][0] = boxes[r0 * 4 + 0];
    s_box[t][1] = boxes[r0 * 4 + 1];
    s_box[t][2] = boxes[r0 * 4 + 2];
    s_box[t][3] = boxes[r0 * 4 + 3];
    s_area[t] = areas[r0];
    __syncthreads();
    int j = bj * 64 + t;
    float jx0 = boxes[j * 4 + 0], jy0 = boxes[j * 4 + 1], jx1 = boxes[j * 4 + 2], jy1 = boxes[j * 4 + 3];
    float ja = areas[j];
    unsigned long long myword = 0ull;
    #pragma unroll 4
    for (int r = 0; r < 64; r++) {
        int i = bi * 64 + r;
        float w = __fsub_rn(fminf(s_box[r][2], jx1), fmaxf(s_box[r][0], jx0));
        float h = __fsub_rn(fminf(s_box[r][3], jy1), fmaxf(s_box[r][1], jy0));
        w = fmaxf(w, 0.0f); h = fmaxf(h, 0.0f);
        float inter = __fmul_rn(w, h);
        float denom = __fadd_rn(__fsub_rn(__fadd_rn(s_area[r], ja), inter), 1e-8f);
        float iou = __fdiv_rn(inter, denom);
        bool sup = (iou > IOU_THR) && (j > i);
        unsigned long long b = __ballot(sup);
        if (t == r) myword = b;
    }
    rowmask[(size_t)(bi * 64 + t) * 64 + bj] = myword;
}

// ---------------- block-diagonal greedy NMS reduce + fused output ----------------
// 1 wave; lane w owns keep word w. LOAD-ALL-64: every row's word w of block b
// is loaded unconditionally (asm-pinned, 128 VGPR forced live via tied-operand
// waits) -- no index extraction, no overflow rounds (R9-R11's hidden cost:
// alive/block ~20-30 > 16 slots => serialized overflow latency every block).
// Addresses depend only on b, so block b+1's 64 loads issue at the end of
// block b and hide under the next phase-1. vmcnt ladder drains 16 at a time.
#define LD(s, ro) \
    asm volatile("global_load_dwordx2 %0, %1, %2" \
                 : "=v"(v##s) : "v"((uint32_t)(((ro) << 9) + wo)), "s"(blk_addr));
#define ISSUE_ALL() \
    LD(0,0) LD(1,1) LD(2,2) LD(3,3) LD(4,4) LD(5,5) LD(6,6) LD(7,7) \
    LD(8,8) LD(9,9) LD(10,10) LD(11,11) LD(12,12) LD(13,13) LD(14,14) LD(15,15) \
    LD(16,16) LD(17,17) LD(18,18) LD(19,19) LD(20,20) LD(21,21) LD(22,22) LD(23,23) \
    LD(24,24) LD(25,25) LD(26,26) LD(27,27) LD(28,28) LD(29,29) LD(30,30) LD(31,31) \
    LD(32,32) LD(33,33) LD(34,34) LD(35,35) LD(36,36) LD(37,37) LD(38,38) LD(39,39) \
    LD(40,40) LD(41,41) LD(42,42) LD(43,43) LD(44,44) LD(45,45) LD(46,46) LD(47,47) \
    LD(48,48) LD(49,49) LD(50,50) LD(51,51) LD(52,52) LD(53,53) LD(54,54) LD(55,55) \
    LD(56,56) LD(57,57) LD(58,58) LD(59,59) LD(60,60) LD(61,61) LD(62,62) LD(63,63)
#define ORR(s) acc |= v##s & ((uint64_t)0 - ((kwv >> (s)) & 1ull));

__global__ __launch_bounds__(64, 1) void k_reduce(const float* __restrict__ topScore,
                         const unsigned long long* __restrict__ rowmask,
                         const float* __restrict__ boxes,
                         const int* __restrict__ Hp, const int* __restrict__ Wp,
                         float* __restrict__ out) {
    __shared__ uint64_t s_diag[4096];   // [block b][lane] = row (64b+lane)'s word b
    int w = threadIdx.x;  // 0..63
    uint32_t wo = (uint32_t)w * 8u;
    uint64_t keep = 0ull;
    #pragma unroll
    for (int c = 0; c < 64; c += 4) {
        float4 s4 = *reinterpret_cast<const float4*>(&topScore[w * 64 + c]);
        keep |= ((uint64_t)(s4.x > 0.0f) << (c + 0))
             |  ((uint64_t)(s4.y > 0.0f) << (c + 1))
             |  ((uint64_t)(s4.z > 0.0f) << (c + 2))
             |  ((uint64_t)(s4.w > 0.0f) << (c + 3));
    }

    // prologue: gather all diagonal words into LDS (4 static groups of 16)
    #pragma unroll
    for (int g = 0; g < 4; g++) {
        uint64_t tt[16];
        #pragma unroll
        for (int k2 = 0; k2 < 16; k2++) {
            int rb = g * 16 + k2;
            tt[k2] = rowmask[(size_t)(rb * 64 + w) * 64 + rb];
        }
        #pragma unroll
        for (int k2 = 0; k2 < 16; k2++) {
            int rb = g * 16 + k2;
            s_diag[rb * 64 + w] = tt[k2];
        }
    }

    uint64_t v0, v1, v2, v3, v4, v5, v6, v7, v8, v9, v10, v11, v12, v13, v14, v15;
    uint64_t v16, v17, v18, v19, v20, v21, v22, v23, v24, v25, v26, v27, v28, v29, v30, v31;
    uint64_t v32, v33, v34, v35, v36, v37, v38, v39, v40, v41, v42, v43, v44, v45, v46, v47;
    uint64_t v48, v49, v50, v51, v52, v53, v54, v55, v56, v57, v58, v59, v60, v61, v62, v63;

    // prologue issue: block 0
    {
        uint64_t blk_addr = (uint64_t)(uintptr_t)rowmask;
        ISSUE_ALL()
        __builtin_amdgcn_sched_barrier(0);
    }

    for (int b = 0; b < 64; b++) {
        // phase 1: scalar within-block suppression (under the batch's load shadow)
        uint64_t kb = readlane64(keep, b);
        uint64_t diag = s_diag[b * 64 + w];
        uint64_t kw = kb, rem = kb;
        while (rem) {
            int i = __builtin_ctzll(rem);
            rem &= rem - 1ull;
            uint64_t row = readlane64(diag, i);
            kw &= ~row;
            rem &= ~row;
        }

        // vmcnt ladder: drain 16 rows at a time; kw rides through wait 1 so the
        // ORs can't float above it and the wait can't move above phase-1
        uint64_t kwv;
        uint64_t acc = 0ull;
        asm volatile("s_waitcnt vmcnt(48)"
            : "=s"(kwv), "+v"(v0), "+v"(v1), "+v"(v2), "+v"(v3),
              "+v"(v4), "+v"(v5), "+v"(v6), "+v"(v7),
              "+v"(v8), "+v"(v9), "+v"(v10), "+v"(v11),
              "+v"(v12), "+v"(v13), "+v"(v14), "+v"(v15)
            : "0"(kw));
        ORR(0) ORR(1) ORR(2) ORR(3) ORR(4) ORR(5) ORR(6) ORR(7)
        ORR(8) ORR(9) ORR(10) ORR(11) ORR(12) ORR(13) ORR(14) ORR(15)
        asm volatile("s_waitcnt vmcnt(32)"
            : "+v"(v16), "+v"(v17), "+v"(v18), "+v"(v19),
              "+v"(v20), "+v"(v21), "+v"(v22), "+v"(v23),
              "+v"(v24), "+v"(v25), "+v"(v26), "+v"(v27),
              "+v"(v28), "+v"(v29), "+v"(v30), "+v"(v31));
        ORR(16) ORR(17) ORR(18) ORR(19) ORR(20) ORR(21) ORR(22) ORR(23)
        ORR(24) ORR(25) ORR(26) ORR(27) ORR(28) ORR(29) ORR(30) ORR(31)
        asm volatile("s_waitcnt vmcnt(16)"
            : "+v"(v32), "+v"(v33), "+v"(v34), "+v"(v35),
              "+v"(v36), "+v"(v37), "+v"(v38), "+v"(v39),
              "+v"(v40), "+v"(v41), "+v"(v42), "+v"(v43),
              "+v"(v44), "+v"(v45), "+v"(v46), "+v"(v47));
        ORR(32) ORR(33) ORR(34) ORR(35) ORR(36) ORR(37) ORR(38) ORR(39)
        ORR(40) ORR(41) ORR(42) ORR(43) ORR(44) ORR(45) ORR(46) ORR(47)
        asm volatile("s_waitcnt vmcnt(0)"
            : "+v"(v48), "+v"(v49), "+v"(v50), "+v"(v51),
              "+v"(v52), "+v"(v53), "+v"(v54), "+v"(v55),
              "+v"(v56), "+v"(v57), "+v"(v58), "+v"(v59),
              "+v"(v60), "+v"(v61), "+v"(v62), "+v"(v63));
        ORR(48) ORR(49) ORR(50) ORR(51) ORR(52) ORR(53) ORR(54) ORR(55)
        ORR(56) ORR(57) ORR(58) ORR(59) ORR(60) ORR(61) ORR(62) ORR(63)

        keep &= ~acc;   // lower-tri words are zero rows; lane b reproduces kw

        // issue next block's 64 rows (addresses independent of keep)
        {
            int nb = (b + 1 < 64) ? (b + 1) : 63;   // b=63: harmless dummy
            uint64_t blk_addr = (uint64_t)(uintptr_t)(rowmask + (size_t)nb * 4096);
            ISSUE_ALL()
            __builtin_amdgcn_sched_barrier(0);
        }
    }

    // fused output: lane w owns rows [w*64, w*64+64)
    float sx = (float)((double)Wp[0] / 1024.0);
    float sy = (float)((double)Hp[0] / 1024.0);
    for (int c = 0; c < 64; c++) {
        int k = w * 64 + c;
        float f = ((keep >> c) & 1ull) ? 1.0f : 0.0f;
        float4 bx = *reinterpret_cast<const float4*>(&boxes[(size_t)k * 4]);
        out[k * 5 + 0] = __fmul_rn(__fmul_rn(bx.x, sx), f);
        out[k * 5 + 1] = __fmul_rn(__fmul_rn(bx.y, sy), f);
        out[k * 5 + 2] = __fmul_rn(__fmul_rn(bx.z, sx), f);
        out[k * 5 + 3] = __fmul_rn(__fmul_rn(bx.w, sy), f);
        out[k * 5 + 4] = __fmul_rn(topScore[k], f);
    }
}

extern "C" void kernel_launch(void* const* d_in, const int* in_sizes, int n_in,
                              void* d_out, int out_size, void* d_ws, size_t ws_size,
                              hipStream_t stream) {
    (void)in_sizes; (void)n_in; (void)out_size; (void)ws_size;
    const float4* cls4   = (const float4*)d_in[0];
    const float* reg     = (const float*)d_in[1];
    const float* anchors = (const float*)d_in[2];
    const int* Hp        = (const int*)d_in[3];
    const int* Wp        = (const int*)d_in[4];
    float* out = (float*)d_out;

    char* ws = (char*)d_ws;
    size_t off = 0;
    auto alloc = [&](size_t bytes) {
        char* p = ws + off;
        off = (off + bytes + 255) & ~(size_t)255;
        return p;
    };
    uint32_t* hist   = (uint32_t*)alloc(BINS * 4);
    uint32_t* ctrs   = (uint32_t*)alloc(64);
    uint64_t* keys   = (uint64_t*)alloc((size_t)CAP * 8);
    float* topScore  = (float*)alloc(KSEL * 4);
    float* boxes     = (float*)alloc(KSEL * 4 * 4);
    float* areas     = (float*)alloc(KSEL * 4);
    unsigned long long* rowmask = (unsigned long long*)alloc((size_t)KSEL * 64 * 8);

    k_init<<<16, 256, 0, stream>>>(hist, ctrs, topScore);
    k_hist<<<2048, 256, 0, stream>>>(cls4, hist);
    k_thresh<<<1, 1024, 0, stream>>>(hist, ctrs);
    k_gather<<<256, 256, 0, stream>>>(cls4, ctrs, keys);
    k_rankdec<<<CAP / 256, 256, 0, stream>>>(keys, ctrs, anchors, reg, topScore, boxes, areas);
    dim3 mg(64, 64);
    k_mask<<<mg, 64, 0, stream>>>(boxes, areas, rowmask);
    k_reduce<<<1, 64, 0, stream>>>(topScore, rowmask, boxes, Hp, Wp, out);
}

// Round 13
// 252.428 us; speedup vs baseline: 1.0522x; 1.0522x over previous
//
#include <hip/hip_runtime.h>
#include <cstdint>

#define N_TOT 1572864
#define KSEL 4096
#define CAP 8192
#define BINS 4096
#define SCORE_THR 0.5f
#define IOU_THR 0.1f
#define STAGE 512

__device__ inline uint64_t readlane64(uint64_t v, int lane) {
    uint32_t lo = (uint32_t)__builtin_amdgcn_readlane((int)(uint32_t)v, lane);
    uint32_t hi = (uint32_t)__builtin_amdgcn_readlane((int)(uint32_t)(v >> 32), lane);
    return ((uint64_t)hi << 32) | lo;
}

// ---------------- init: zero hist/counters/topScore ----------------
__global__ void k_init(uint32_t* hist, uint32_t* ctrs, float* topScore) {
    int i = blockIdx.x * blockDim.x + threadIdx.x;
    if (i < BINS) hist[i] = 0;
    if (i < 16) ctrs[i] = 0;
    if (i < KSEL) topScore[i] = 0.0f;
}

// ---------------- histogram over score bits (scores in (0.5,1)), float4 stream ----------------
__global__ void k_hist(const float4* __restrict__ cls4, uint32_t* __restrict__ hist) {
    int i = blockIdx.x * blockDim.x + threadIdx.x;
    int stride = gridDim.x * blockDim.x;
    for (; i < N_TOT / 2; i += stride) {
        float4 c = cls4[i];
        if (c.y > SCORE_THR) {
            uint32_t bin = (__float_as_uint(c.y) - 0x3F000000u) >> 11;
            if (bin >= BINS) bin = BINS - 1;
            atomicAdd(&hist[bin], 1u);
        }
        if (c.w > SCORE_THR) {
            uint32_t bin = (__float_as_uint(c.w) - 0x3F000000u) >> 11;
            if (bin >= BINS) bin = BINS - 1;
            atomicAdd(&hist[bin], 1u);
        }
    }
}

// ---------------- find cutoff bin T: largest b with suffix(b) >= K ----------------
__global__ __launch_bounds__(1024) void k_thresh(const uint32_t* __restrict__ hist,
                                                 uint32_t* __restrict__ ctrs) {
    __shared__ uint32_t s_suf[1024];
    int t = threadIdx.x;
    uint32_t l0 = hist[t*4+0], l1 = hist[t*4+1], l2 = hist[t*4+2], l3 = hist[t*4+3];
    s_suf[t] = l0 + l1 + l2 + l3;
    __syncthreads();
    for (int off = 1; off < 1024; off <<= 1) {
        uint32_t v = (t + off < 1024) ? s_suf[t + off] : 0u;
        __syncthreads();
        s_suf[t] += v;
        __syncthreads();
    }
    uint32_t snext = (t < 1023) ? s_suf[t + 1] : 0u;
    uint32_t suf3 = snext + l3;
    uint32_t suf2 = suf3 + l2;
    uint32_t suf1 = suf2 + l1;
    uint32_t suf0 = suf1 + l0;
    uint32_t sufs[5] = {suf0, suf1, suf2, suf3, snext};
    #pragma unroll
    for (int q = 0; q < 4; q++) {
        if (sufs[q] >= KSEL && sufs[q+1] < KSEL) ctrs[1] = (uint32_t)(t*4 + q);
    }
    if (t == 0 && s_suf[0] < KSEL) ctrs[1] = 0;  // fewer than K candidates
}

// ---------------- gather candidates (bin >= T) via LDS staging; 1 global atomic/block ----------------
__global__ void k_gather(const float4* __restrict__ cls4, uint32_t* __restrict__ ctrs,
                         uint64_t* __restrict__ keys) {
    __shared__ uint32_t s_cnt;
    __shared__ uint32_t s_base;
    __shared__ uint64_t s_stage[STAGE];
    if (threadIdx.x == 0) s_cnt = 0;
    __syncthreads();

    uint32_t T = ctrs[1];
    uint32_t basebits = 0x3F000000u + (T << 11);
    int i = blockIdx.x * blockDim.x + threadIdx.x;
    int stride = gridDim.x * blockDim.x;
    for (; i < N_TOT / 2; i += stride) {
        float4 c = cls4[i];
        #pragma unroll
        for (int h = 0; h < 2; h++) {
            float s = h ? c.w : c.y;
            uint32_t idx = 2u * (uint32_t)i + (uint32_t)h;
            if (s > SCORE_THR) {
                uint32_t b = __float_as_uint(s);
                if (b >= basebits) {
                    uint64_t key = ((uint64_t)b << 32) | (uint32_t)(~idx);
                    uint32_t p = atomicAdd(&s_cnt, 1u);
                    if (p < STAGE) s_stage[p] = key;
                    else {  // overflow: rare fallback, correctness-preserving
                        uint32_t g = atomicAdd(&ctrs[0], 1u);
                        if (g < CAP) keys[g] = key;
                    }
                }
            }
        }
    }
    __syncthreads();
    uint32_t n = s_cnt < STAGE ? s_cnt : STAGE;
    if (threadIdx.x == 0 && n > 0) s_base = atomicAdd(&ctrs[0], n);
    __syncthreads();
    for (uint32_t q = threadIdx.x; q < n; q += blockDim.x) {
        uint32_t g = s_base + q;
        if (g < CAP) keys[g] = s_stage[q];
    }
}

// ---------------- exact rank sort + fused decode (numpy f32 rounding, no FMA) ----------------
__global__ void k_rankdec(const uint64_t* __restrict__ keys, const uint32_t* __restrict__ ctrs,
                          const float* __restrict__ anchors, const float* __restrict__ reg,
                          float* __restrict__ topScore, float* __restrict__ boxes,
                          float* __restrict__ areas) {
    __shared__ uint64_t s_keys[256];
    uint32_t M = ctrs[0]; if (M > CAP) M = CAP;
    int j = blockIdx.x * blockDim.x + threadIdx.x;
    uint64_t myKey = (j < (int)M) ? keys[j] : 0ull;
    uint32_t rank = 0;
    for (uint32_t base = 0; base < M; base += 256) {
        uint32_t idx = base + threadIdx.x;
        s_keys[threadIdx.x] = (idx < M) ? keys[idx] : 0ull;
        __syncthreads();
        uint32_t lim = min(256u, M - base);
        for (uint32_t q = 0; q < lim; q++)
            rank += (s_keys[q] > myKey) ? 1u : 0u;
        __syncthreads();
    }
    if (j < (int)M && rank < KSEL) {
        uint32_t srcIdx = ~((uint32_t)(myKey & 0xFFFFFFFFull));
        topScore[rank] = __uint_as_float((uint32_t)(myKey >> 32));
        float4 a = *reinterpret_cast<const float4*>(&anchors[(size_t)srcIdx * 4]);
        float4 dd = *reinterpret_cast<const float4*>(&reg[(size_t)srcIdx * 4]);
        float d0 = __fmul_rn(dd.x, 0.1f);
        float d1 = __fmul_rn(dd.y, 0.1f);
        float d2 = __fmul_rn(dd.z, 0.2f);
        float d3 = __fmul_rn(dd.w, 0.2f);
        float w  = __fsub_rn(a.z, a.x);
        float h  = __fsub_rn(a.w, a.y);
        float cx = __fadd_rn(a.x, __fmul_rn(0.5f, w));
        float cy = __fadd_rn(a.y, __fmul_rn(0.5f, h));
        float pcx = __fadd_rn(cx, __fmul_rn(d0, w));
        float pcy = __fadd_rn(cy, __fmul_rn(d1, h));
        float pw = __fmul_rn((float)exp((double)d2), w);
        float ph = __fmul_rn((float)exp((double)d3), h);
        float x0 = __fsub_rn(pcx, __fmul_rn(0.5f, pw));
        float y0 = __fsub_rn(pcy, __fmul_rn(0.5f, ph));
        float x1 = __fadd_rn(pcx, __fmul_rn(0.5f, pw));
        float y1 = __fadd_rn(pcy, __fmul_rn(0.5f, ph));
        x0 = fminf(fmaxf(x0, 0.0f), 1024.0f);
        y0 = fminf(fmaxf(y0, 0.0f), 1024.0f);
        x1 = fminf(fmaxf(x1, 0.0f), 1024.0f);
        y1 = fminf(fmaxf(y1, 0.0f), 1024.0f);
        *reinterpret_cast<float4*>(&boxes[(size_t)rank * 4]) = make_float4(x0, y0, x1, y1);
        areas[rank] = __fmul_rn(__fsub_rn(x1, x0), __fsub_rn(y1, y0));
    }
}

// ---------------- pairwise suppression bitmask; lower-triangle blocks write 0 ----------------
__global__ void k_mask(const float* __restrict__ boxes, const float* __restrict__ areas,
                       unsigned long long* __restrict__ rowmask) {
    int bi = blockIdx.y, bj = blockIdx.x;
    int t = threadIdx.x;
    if (bj < bi) {  // zero-fill so reduce can AND rows unguarded
        rowmask[(size_t)(bi * 64 + t) * 64 + bj] = 0ull;
        return;
    }
    __shared__ float s_box[64][4];
    __shared__ float s_area[64];
    int r0 = bi * 64 + t;
    s_box[t][0] = boxes[r0 * 4 + 0];
    s_box[t][1] = boxes[r0 * 4 + 1];
    s_box[t][2] = boxes[r0 * 4 + 2];
    s_box[t][3] = boxes[r0 * 4 + 3];
    s_area[t] = areas[r0];
    __syncthreads();
    int j = bj * 64 + t;
    float jx0 = boxes[j * 4 + 0], jy0 = boxes[j * 4 + 1], jx1 = boxes[j * 4 + 2], jy1 = boxes[j * 4 + 3];
    float ja = areas[j];
    unsigned long long myword = 0ull;
    #pragma unroll 4
    for (int r = 0; r < 64; r++) {
        int i = bi * 64 + r;
        float w = __fsub_rn(fminf(s_box[r][2], jx1), fmaxf(s_box[r][0], jx0));
        float h = __fsub_rn(fminf(s_box[r][3], jy1), fmaxf(s_box[r][1], jy0));
        w = fmaxf(w, 0.0f); h = fmaxf(h, 0.0f);
        float inter = __fmul_rn(w, h);
        float denom = __fadd_rn(__fsub_rn(__fadd_rn(s_area[r], ja), inter), 1e-8f);
        float iou = __fdiv_rn(inter, denom);
        bool sup = (iou > IOU_THR) && (j > i);
        unsigned long long b = __ballot(sup);
        if (t == r) myword = b;
    }
    rowmask[(size_t)(bi * 64 + t) * 64 + bj] = myword;
}

// ---------------- 16-wave cooperative block-diagonal NMS reduce + fused output ----------------
// 1024 threads. Thread (g = t>>6, w = t&63) owns rows g*4..g*4+3 (word w) of each
// block -- coalesced loads. Register tiles, prefetch depth 4 blocks (16
// outstanding/thread << vmcnt cap 63; single-wave designs R9-R12 hit the 64-op
// vmcnt wall ~ 35GB/s). Raw s_barrier + counted vmcnt(12) lets loads span
// barriers (HK T3/T4). Phase-1 runs redundantly on all waves (wave-uniform);
// s_keep update is idempotent so redundant writes are benign.
#define ISSUEB(p, nb) { \
    uint64_t blk = rm_base + (uint64_t)(nb) * 32768ull; \
    asm volatile("global_load_dwordx2 %0, %1, %2" : "=v"(p##0) : "v"(voff0), "s"(blk)); \
    asm volatile("global_load_dwordx2 %0, %1, %2" : "=v"(p##1) : "v"(voff1), "s"(blk)); \
    asm volatile("global_load_dwordx2 %0, %1, %2" : "=v"(p##2) : "v"(voff2), "s"(blk)); \
    asm volatile("global_load_dwordx2 %0, %1, %2" : "=v"(p##3) : "v"(voff3), "s"(blk)); \
}

#define STEP(bidx, p) { \
    int b_ = (bidx); \
    uint64_t kb = s_keep[b_]; \
    uint64_t diag = s_diag[b_][w]; \
    uint64_t kw = kb, rem = kb; \
    while (rem) { \
        int i_ = __builtin_ctzll(rem); \
        rem &= rem - 1ull; \
        uint64_t row = readlane64(diag, i_); \
        kw &= ~row; rem &= ~row; \
    } \
    uint64_t kwv; \
    asm volatile("s_waitcnt vmcnt(12)" \
        : "=v"(kwv), "+v"(p##0), "+v"(p##1), "+v"(p##2), "+v"(p##3) : "0"(kw)); \
    uint64_t part = (p##0 & (0ull - ((kwv >> (g * 4 + 0)) & 1ull))) \
                  | (p##1 & (0ull - ((kwv >> (g * 4 + 1)) & 1ull))) \
                  | (p##2 & (0ull - ((kwv >> (g * 4 + 2)) & 1ull))) \
                  | (p##3 & (0ull - ((kwv >> (g * 4 + 3)) & 1ull))); \
    s_part[g][w] = part; \
    int nb_ = b_ + 4; if (nb_ > 63) nb_ = 63; \
    ISSUEB(p, nb_) \
    asm volatile("s_waitcnt lgkmcnt(0)" ::: "memory"); \
    __builtin_amdgcn_s_barrier(); \
    __builtin_amdgcn_sched_barrier(0); \
    uint64_t acc = 0ull; \
    _Pragma("unroll") \
    for (int gg = 0; gg < 16; gg++) acc |= s_part[gg][w]; \
    uint64_t nk = s_keep[w] & ~acc; \
    s_keep[w] = nk; \
    asm volatile("s_waitcnt lgkmcnt(0)" ::: "memory"); \
    __builtin_amdgcn_s_barrier(); \
    __builtin_amdgcn_sched_barrier(0); \
}

__global__ __launch_bounds__(1024, 1) void k_reduce(const float* __restrict__ topScore,
                         const unsigned long long* __restrict__ rowmask,
                         const float* __restrict__ boxes,
                         const int* __restrict__ Hp, const int* __restrict__ Wp,
                         float* __restrict__ out) {
    __shared__ uint64_t s_diag[64][64];   // 32 KB: [block][lane] = row's diag word
    __shared__ uint64_t s_part[16][64];   // 8 KB: per-group partial ORs
    __shared__ uint64_t s_keep[64];
    int t = threadIdx.x;
    int w = t & 63;
    int g = t >> 6;   // 0..15

    uint32_t voff0 = (uint32_t)((g * 256 + 0 * 64 + w) * 8);
    uint32_t voff1 = (uint32_t)((g * 256 + 1 * 64 + w) * 8);
    uint32_t voff2 = (uint32_t)((g * 256 + 2 * 64 + w) * 8);
    uint32_t voff3 = (uint32_t)((g * 256 + 3 * 64 + w) * 8);
    uint64_t rm_base = (uint64_t)(uintptr_t)rowmask;

    // prologue: diag gather (all waves) + keep init (wave 0)
    #pragma unroll
    for (int q = 0; q < 4; q++) {
        int bb = g * 4 + q;
        s_diag[bb][w] = rowmask[(size_t)(bb * 64 + w) * 64 + bb];
    }
    if (g == 0) {
        uint64_t keep = 0ull;
        #pragma unroll
        for (int c = 0; c < 64; c += 4) {
            float4 s4 = *reinterpret_cast<const float4*>(&topScore[w * 64 + c]);
            keep |= ((uint64_t)(s4.x > 0.0f) << (c + 0))
                 |  ((uint64_t)(s4.y > 0.0f) << (c + 1))
                 |  ((uint64_t)(s4.z > 0.0f) << (c + 2))
                 |  ((uint64_t)(s4.w > 0.0f) << (c + 3));
        }
        s_keep[w] = keep;
    }
    __syncthreads();   // one-time full drain: all prologue loads/stores settled

    uint64_t a0, a1, a2, a3, b0, b1, b2, b3;
    uint64_t c0, c1, c2, c3, d0, d1, d2, d3;
    ISSUEB(a, 0) ISSUEB(b, 1) ISSUEB(c, 2) ISSUEB(d, 3)
    __builtin_amdgcn_sched_barrier(0);

    for (int bb = 0; bb < 64; bb += 4) {
        STEP(bb + 0, a)
        STEP(bb + 1, b)
        STEP(bb + 2, c)
        STEP(bb + 3, d)
    }
    asm volatile("s_waitcnt vmcnt(0)" ::: "memory");   // retire dummy tail loads

    // fused output: 1024 threads x 4 candidates
    float sx = (float)((double)Wp[0] / 1024.0);
    float sy = (float)((double)Hp[0] / 1024.0);
    #pragma unroll
    for (int q = 0; q < 4; q++) {
        int k = t * 4 + q;
        float f = ((s_keep[k >> 6] >> (k & 63)) & 1ull) ? 1.0f : 0.0f;
        float4 bx = *reinterpret_cast<const float4*>(&boxes[(size_t)k * 4]);
        out[k * 5 + 0] = __fmul_rn(__fmul_rn(bx.x, sx), f);
        out[k * 5 + 1] = __fmul_rn(__fmul_rn(bx.y, sy), f);
        out[k * 5 + 2] = __fmul_rn(__fmul_rn(bx.z, sx), f);
        out[k * 5 + 3] = __fmul_rn(__fmul_rn(bx.w, sy), f);
        out[k * 5 + 4] = __fmul_rn(topScore[k], f);
    }
}

extern "C" void kernel_launch(void* const* d_in, const int* in_sizes, int n_in,
                              void* d_out, int out_size, void* d_ws, size_t ws_size,
                              hipStream_t stream) {
    (void)in_sizes; (void)n_in; (void)out_size; (void)ws_size;
    const float4* cls4   = (const float4*)d_in[0];
    const float* reg     = (const float*)d_in[1];
    const float* anchors = (const float*)d_in[2];
    const int* Hp        = (const int*)d_in[3];
    const int* Wp        = (const int*)d_in[4];
    float* out = (float*)d_out;

    char* ws = (char*)d_ws;
    size_t off = 0;
    auto alloc = [&](size_t bytes) {
        char* p = ws + off;
        off = (off + bytes + 255) & ~(size_t)255;
        return p;
    };
    uint32_t* hist   = (uint32_t*)alloc(BINS * 4);
    uint32_t* ctrs   = (uint32_t*)alloc(64);
    uint64_t* keys   = (uint64_t*)alloc((size_t)CAP * 8);
    float* topScore  = (float*)alloc(KSEL * 4);
    float* boxes     = (float*)alloc(KSEL * 4 * 4);
    float* areas     = (float*)alloc(KSEL * 4);
    unsigned long long* rowmask = (unsigned long long*)alloc((size_t)KSEL * 64 * 8);

    k_init<<<16, 256, 0, stream>>>(hist, ctrs, topScore);
    k_hist<<<2048, 256, 0, stream>>>(cls4, hist);
    k_thresh<<<1, 1024, 0, stream>>>(hist, ctrs);
    k_gather<<<256, 256, 0, stream>>>(cls4, ctrs, keys);
    k_rankdec<<<CAP / 256, 256, 0, stream>>>(keys, ctrs, anchors, reg, topScore, boxes, areas);
    dim3 mg(64, 64);
    k_mask<<<mg, 64, 0, stream>>>(boxes, areas, rowmask);
    k_reduce<<<1, 1024, 0, stream>>>(topScore, rowmask, boxes, Hp, Wp, out);
}